// Round 6
// baseline (281.781 us; speedup 1.0000x reference)
//
#include <hip/hip_runtime.h>

#define BB 512
#define TT 512
#define NTAG 64

// Broadcast lane `l`'s value of v to all lanes via v_readlane (SGPR dest).
#define BCAST(v, l) __uint_as_float((unsigned)__builtin_amdgcn_readlane((int)__float_as_uint(v), (l)))

#define DECL4(a,b,c,d) \
    float e##a = __expf(trans[a * NTAG + j]); \
    float e##b = __expf(trans[b * NTAG + j]); \
    float e##c = __expf(trans[c * NTAG + j]); \
    float e##d = __expf(trans[d * NTAG + j]);

// Make e_i opaque: empty asm with "+v" redefines the value, so the register
// allocator CANNOT rematerialize the load+exp chain inside the loop (which is
// what it did in R3-R5: VGPR_Count=44, loads+v_exp sunk into the hot loop,
// ~1000 cyc/step). Forces genuine VGPR residency. Zero dynamic cost.
#define KEEP16(a) \
    asm("" : "+v"(e##a##0), "+v"(e##a##1), "+v"(e##a##2), "+v"(e##a##3), \
             "+v"(e##a##4), "+v"(e##a##5), "+v"(e##a##6), "+v"(e##a##7), \
             "+v"(e##a##8), "+v"(e##a##9));

#define FMA4(a,b,c,d) \
    sA = fmaf(BCAST(x, a), e##a, sA); \
    sB = fmaf(BCAST(x, b), e##b, sB); \
    sC = fmaf(BCAST(x, c), e##c, sC); \
    sD = fmaf(BCAST(x, d), e##d, sD);

__global__ __launch_bounds__(64, 1) void crf_kernel(
    const float* __restrict__ inputs,   // [B,T,N] f32
    const float* __restrict__ trans,    // [N,N]   f32
    const int*   __restrict__ tags,     // [B,T]   i32
    const int*   __restrict__ lens,     // [B]     i32
    float*       __restrict__ out)      // [B]     f32 (log_likelihood)
{
    const int b = blockIdx.x;
    const int j = threadIdx.x;           // 0..63
    const int len  = lens[b];
    const int last = (len - 1) > 0 ? (len - 1) : 0;

    // ---------------- sequence score (gathers) ----------------
    float sc = 0.f;
    #pragma unroll
    for (int tt = 0; tt < TT / 64; ++tt) {
        const int t = tt * 64 + j;
        if (t < len) {
            const int tg = tags[b * TT + t];
            sc += inputs[(size_t)b * TT * NTAG + (size_t)t * NTAG + tg];
            if (t >= 1) {
                const int tp = tags[b * TT + t - 1];
                sc += trans[tp * NTAG + tg];
            }
        }
    }
    #pragma unroll
    for (int m = 32; m >= 1; m >>= 1) sc += __shfl_xor(sc, m);

    // ---------------- E[:,j] = exp(trans[:,j]) into registers --------------
    DECL4(0,1,2,3)   DECL4(4,5,6,7)   DECL4(8,9,10,11)  DECL4(12,13,14,15)
    DECL4(16,17,18,19) DECL4(20,21,22,23) DECL4(24,25,26,27) DECL4(28,29,30,31)
    DECL4(32,33,34,35) DECL4(36,37,38,39) DECL4(40,41,42,43) DECL4(44,45,46,47)
    DECL4(48,49,50,51) DECL4(52,53,54,55) DECL4(56,57,58,59) DECL4(60,61,62,63)

    // Force VGPR residency of all 64 e-values (see KEEP16 comment).
    asm("" : "+v"(e0), "+v"(e1), "+v"(e2), "+v"(e3), "+v"(e4), "+v"(e5),
             "+v"(e6), "+v"(e7), "+v"(e8), "+v"(e9), "+v"(e10), "+v"(e11),
             "+v"(e12), "+v"(e13), "+v"(e14), "+v"(e15));
    asm("" : "+v"(e16), "+v"(e17), "+v"(e18), "+v"(e19), "+v"(e20), "+v"(e21),
             "+v"(e22), "+v"(e23), "+v"(e24), "+v"(e25), "+v"(e26), "+v"(e27),
             "+v"(e28), "+v"(e29), "+v"(e30), "+v"(e31));
    asm("" : "+v"(e32), "+v"(e33), "+v"(e34), "+v"(e35), "+v"(e36), "+v"(e37),
             "+v"(e38), "+v"(e39), "+v"(e40), "+v"(e41), "+v"(e42), "+v"(e43),
             "+v"(e44), "+v"(e45), "+v"(e46), "+v"(e47));
    asm("" : "+v"(e48), "+v"(e49), "+v"(e50), "+v"(e51), "+v"(e52), "+v"(e53),
             "+v"(e54), "+v"(e55), "+v"(e56), "+v"(e57), "+v"(e58), "+v"(e59),
             "+v"(e60), "+v"(e61), "+v"(e62), "+v"(e63));

    // ---------------- forward recurrence ----------------
    const float* emit = inputs + (size_t)b * TT * NTAG;
    float alpha = emit[j];

    // register prefetch ring, distance 3; clamped index is the OOB guard.
    float pre0 = emit[(size_t)min(1, last) * NTAG + j];
    float pre1 = emit[(size_t)min(2, last) * NTAG + j];
    float pre2 = emit[(size_t)min(3, last) * NTAG + j];

    for (int t = 1; t <= last; ++t) {
        const float cur = pre0;
        pre0 = pre1;
        pre1 = pre2;
        pre2 = emit[(size_t)min(t + 3, last) * NTAG + j];

        // C = any uniform shift; lane-0 alpha is within ~20 of the max
        // (spread bounded by emission + transition column spread), so
        // exp stays comfortably in f32 range.
        const float C = BCAST(alpha, 0);

        const float x = __expf(alpha - C);

        // s_j = sum_i x_i * E[i][j] — v_readlane broadcast (SGPR) feeds
        // v_fmac_f32 directly; 4 partial chains shorten the critical path.
        float sA = 0.f, sB = 0.f, sC = 0.f, sD = 0.f;
        FMA4(0,1,2,3)   FMA4(4,5,6,7)   FMA4(8,9,10,11)  FMA4(12,13,14,15)
        FMA4(16,17,18,19) FMA4(20,21,22,23) FMA4(24,25,26,27) FMA4(28,29,30,31)
        FMA4(32,33,34,35) FMA4(36,37,38,39) FMA4(40,41,42,43) FMA4(44,45,46,47)
        FMA4(48,49,50,51) FMA4(52,53,54,55) FMA4(56,57,58,59) FMA4(60,61,62,63)
        const float s = (sA + sB) + (sC + sD);

        alpha = cur + C + __logf(s);
    }

    // final logsumexp over lanes (exact max here — runs once)
    float C2 = alpha;
    #pragma unroll
    for (int m = 32; m >= 1; m >>= 1) C2 = fmaxf(C2, __shfl_xor(C2, m));
    float xs = __expf(alpha - C2);
    #pragma unroll
    for (int m = 32; m >= 1; m >>= 1) xs += __shfl_xor(xs, m);
    const float lognorm = C2 + __logf(xs);

    if (j == 0) out[b] = sc - lognorm;
}

__global__ __launch_bounds__(256) void copy_trans_kernel(
    const float* __restrict__ trans, float* __restrict__ out)
{
    const int k = blockIdx.x * 256 + threadIdx.x;
    if (k < NTAG * NTAG) out[k] = trans[k];
}

extern "C" void kernel_launch(void* const* d_in, const int* in_sizes, int n_in,
                              void* d_out, int out_size, void* d_ws, size_t ws_size,
                              hipStream_t stream) {
    const float* inputs = (const float*)d_in[0];
    const float* trans  = (const float*)d_in[1];
    const int*   tags   = (const int*)d_in[2];
    const int*   lens   = (const int*)d_in[3];
    float* out = (float*)d_out;

    crf_kernel<<<BB, 64, 0, stream>>>(inputs, trans, tags, lens, out);
    copy_trans_kernel<<<(NTAG * NTAG + 255) / 256, 256, 0, stream>>>(trans, out + BB);
}